// Round 1
// baseline (579.763 us; speedup 1.0000x reference)
//
#include <hip/hip_runtime.h>
#include <hip/hip_bf16.h>

typedef __bf16 bf16x8 __attribute__((ext_vector_type(8)));
typedef __bf16 bf16x4 __attribute__((ext_vector_type(4)));
typedef float  f32x4  __attribute__((ext_vector_type(4)));

#define MIN_VALUE (-1.7014118346046923e38f)

// ---------------------------------------------------------------- split x -> bf16 hi/lo
__global__ __launch_bounds__(256) void split_x_kernel(const float* __restrict__ x,
                                                      __bf16* __restrict__ xh,
                                                      __bf16* __restrict__ xl) {
    int i = (blockIdx.x * 256 + threadIdx.x) * 4;
    float4 v = *(const float4*)(x + i);
    float vv[4] = {v.x, v.y, v.z, v.w};
    bf16x4 h, l;
    for (int e = 0; e < 4; ++e) {
        __bf16 hi = (__bf16)vv[e];
        h[e] = hi;
        l[e] = (__bf16)(vv[e] - (float)hi);
    }
    *(bf16x4*)(xh + i) = h;
    *(bf16x4*)(xl + i) = l;
}

// ------------------------------------------- transpose+split Wq/Wk/Wv -> [3072][1024] hi/lo
// out row n = sel*1024 + h*64 + d, col = i.  Input W[h][i][d] ([16][1024][64]).
__global__ __launch_bounds__(256) void split_w_kernel(const float* __restrict__ Wq,
                                                      const float* __restrict__ Wk,
                                                      const float* __restrict__ Wv,
                                                      __bf16* __restrict__ wh,
                                                      __bf16* __restrict__ wl) {
    __shared__ float t[32][33];
    int z = blockIdx.z;
    int sel = z >> 4, h = z & 15;
    const float* W = (sel == 0) ? Wq : (sel == 1) ? Wk : Wv;
    int i0 = blockIdx.x * 32, d0 = blockIdx.y * 32;
    int tx = threadIdx.x & 31, ty = threadIdx.x >> 5;  // 8 rows per pass
    for (int it = 0; it < 4; ++it) {
        int r = ty + it * 8;
        t[r][tx] = W[(size_t)(h * 1024 + i0 + r) * 64 + d0 + tx];
    }
    __syncthreads();
    for (int it = 0; it < 4; ++it) {
        int r = ty + it * 8;
        float v = t[tx][r];  // = W[h][i0+tx][d0+r]
        size_t o = (size_t)(sel * 1024 + h * 64 + d0 + r) * 1024 + i0 + tx;
        __bf16 hi = (__bf16)v;
        wh[o] = hi;
        wl[o] = (__bf16)(v - (float)hi);
    }
}

// ---------------------------------------------------------------- Wo -> bf16 (natural [n][k])
__global__ __launch_bounds__(256) void conv_wo_kernel(const float* __restrict__ Wo,
                                                      __bf16* __restrict__ wob) {
    int i = (blockIdx.x * 256 + threadIdx.x) * 4;
    float4 v = *(const float4*)(Wo + i);
    float vv[4] = {v.x, v.y, v.z, v.w};
    bf16x4 h;
    for (int e = 0; e < 4; ++e) h[e] = (__bf16)vv[e];
    *(bf16x4*)(wob + i) = h;
}

// ---------------------------------------------------------------- QKV GEMM (hi/lo split)
// C[4096][3072] = x[4096][1024] @ Wt^T ; Wt is [3072][1024] ([n][k]).
// Outputs: q,k as bf16 [bh][l][64]; v transposed bf16 [bh][d][1024].
__global__ __launch_bounds__(256) void qkv_gemm_kernel(
    const __bf16* __restrict__ xh, const __bf16* __restrict__ xl,
    const __bf16* __restrict__ wh, const __bf16* __restrict__ wl,
    const float* __restrict__ bq, const float* __restrict__ bk, const float* __restrict__ bv,
    __bf16* __restrict__ qb, __bf16* __restrict__ kb, __bf16* __restrict__ vtb) {
    __shared__ __bf16 As[2][128 * 32];
    __shared__ __bf16 Bs[2][128 * 32];
    const int tid = threadIdx.x;
    const int m0 = blockIdx.y * 128;
    const int n0 = blockIdx.x * 128;
    const int lane = tid & 63, w = tid >> 6;
    const int l15 = lane & 15, quad = lane >> 4;
    const int wm = (w & 1) * 64, wn = (w >> 1) * 64;

    f32x4 acc[4][4];
    for (int i = 0; i < 4; ++i)
        for (int j = 0; j < 4; ++j)
            for (int r = 0; r < 4; ++r) acc[i][j][r] = 0.0f;

    for (int kk = 0; kk < 1024; kk += 32) {
        __syncthreads();
        for (int cc = 0; cc < 2; ++cc) {
            int c = tid + cc * 256;
            int row = c >> 2, k8 = (c & 3) * 8;
            *(bf16x8*)&As[0][row * 32 + k8] = *(const bf16x8*)&xh[(size_t)(m0 + row) * 1024 + kk + k8];
            *(bf16x8*)&As[1][row * 32 + k8] = *(const bf16x8*)&xl[(size_t)(m0 + row) * 1024 + kk + k8];
            *(bf16x8*)&Bs[0][row * 32 + k8] = *(const bf16x8*)&wh[(size_t)(n0 + row) * 1024 + kk + k8];
            *(bf16x8*)&Bs[1][row * 32 + k8] = *(const bf16x8*)&wl[(size_t)(n0 + row) * 1024 + kk + k8];
        }
        __syncthreads();
        bf16x8 af[4][2], bfr[4][2];
        for (int i = 0; i < 4; ++i) {
            af[i][0] = *(const bf16x8*)&As[0][(wm + i * 16 + l15) * 32 + quad * 8];
            af[i][1] = *(const bf16x8*)&As[1][(wm + i * 16 + l15) * 32 + quad * 8];
        }
        for (int j = 0; j < 4; ++j) {
            bfr[j][0] = *(const bf16x8*)&Bs[0][(wn + j * 16 + l15) * 32 + quad * 8];
            bfr[j][1] = *(const bf16x8*)&Bs[1][(wn + j * 16 + l15) * 32 + quad * 8];
        }
        for (int i = 0; i < 4; ++i)
            for (int j = 0; j < 4; ++j) {
                acc[i][j] = __builtin_amdgcn_mfma_f32_16x16x32_bf16(af[i][0], bfr[j][0], acc[i][j], 0, 0, 0);
                acc[i][j] = __builtin_amdgcn_mfma_f32_16x16x32_bf16(af[i][0], bfr[j][1], acc[i][j], 0, 0, 0);
                acc[i][j] = __builtin_amdgcn_mfma_f32_16x16x32_bf16(af[i][1], bfr[j][0], acc[i][j], 0, 0, 0);
            }
    }

    const int sel = n0 >> 10;
    const float* bias = (sel == 0) ? bq : (sel == 1) ? bk : bv;
    for (int i = 0; i < 4; ++i)
        for (int j = 0; j < 4; ++j)
            for (int r = 0; r < 4; ++r) {
                int m = m0 + wm + i * 16 + quad * 4 + r;
                int n = n0 + wn + j * 16 + l15;
                int nn = n & 1023;
                int h = nn >> 6, d = n & 63;
                float v = acc[i][j][r] + bias[nn];
                int bb = m >> 10, ll = m & 1023;
                if (sel == 2) {
                    vtb[(size_t)((bb * 16 + h) * 64 + d) * 1024 + ll] = (__bf16)v;
                } else {
                    __bf16* dst = (sel == 0) ? qb : kb;
                    dst[(size_t)((bb * 16 + h) * 1024 + ll) * 64 + d] = (__bf16)v;
                }
            }
}

// --------------------------------------- fused scores + mask + softmax + PV per 16-row tile
__global__ __launch_bounds__(256) void attn_kernel(
    const __bf16* __restrict__ qb, const __bf16* __restrict__ kb,
    const __bf16* __restrict__ vtb, const int* __restrict__ mask,
    float* __restrict__ atten, __bf16* __restrict__ value_bf) {
    __shared__ float S[16 * 1024];  // exactly 64 KB
    const int m0 = blockIdx.x * 16;
    const int h = blockIdx.y, b = blockIdx.z;
    const int bh = b * 16 + h;
    const int tid = threadIdx.x;
    const int lane = tid & 63, w = tid >> 6;
    const int l15 = lane & 15, quad = lane >> 4;

    // phase 1: S = (q @ k^T) * scale, masked
    const __bf16* qbase = qb + (size_t)(bh * 1024 + m0 + l15) * 64 + quad * 8;
    bf16x8 a0 = *(const bf16x8*)(qbase);
    bf16x8 a1 = *(const bf16x8*)(qbase + 32);
    for (int t = 0; t < 16; ++t) {
        int n0 = w * 256 + t * 16;
        const __bf16* kbase = kb + (size_t)(bh * 1024 + n0 + l15) * 64 + quad * 8;
        bf16x8 b0 = *(const bf16x8*)(kbase);
        bf16x8 b1 = *(const bf16x8*)(kbase + 32);
        f32x4 c = {0.f, 0.f, 0.f, 0.f};
        c = __builtin_amdgcn_mfma_f32_16x16x32_bf16(a0, b0, c, 0, 0, 0);
        c = __builtin_amdgcn_mfma_f32_16x16x32_bf16(a1, b1, c, 0, 0, 0);
        int col = n0 + l15;
        bool msk = (mask[b * 1024 + col] == 0);
        for (int r = 0; r < 4; ++r) {
            float s = c[r] * 0.125f;
            if (msk) s = MIN_VALUE;
            S[(quad * 4 + r) * 1024 + col] = s;
        }
    }
    __syncthreads();

    // phase 2: softmax on rows 4w..4w+3 (values held in registers)
    float p[4][16];
    float invs[4];
    for (int j = 0; j < 4; ++j) {
        int row = w * 4 + j;
        float mx = -3.4e38f;
        for (int i = 0; i < 16; ++i) {
            p[j][i] = S[row * 1024 + i * 64 + lane];
            mx = fmaxf(mx, p[j][i]);
        }
        for (int o = 32; o > 0; o >>= 1) mx = fmaxf(mx, __shfl_xor(mx, o));
        float sum = 0.f;
        for (int i = 0; i < 16; ++i) {
            float e = __expf(p[j][i] - mx);
            p[j][i] = e;
            sum += e;
        }
        for (int o = 32; o > 0; o >>= 1) sum += __shfl_xor(sum, o);
        float inv = 1.0f / sum;
        invs[j] = inv;
        float* out = atten + (size_t)(bh * 1024 + m0 + row) * 1024;
        for (int i = 0; i < 16; ++i) {
            p[j][i] *= inv;
            out[i * 64 + lane] = p[j][i];
        }
    }
    __syncthreads();

    // repack P to bf16 in LDS, row stride 1040 (16B aligned, low-conflict)
    __bf16* Sb = (__bf16*)S;
    for (int j = 0; j < 4; ++j) {
        int row = w * 4 + j;
        for (int i = 0; i < 16; ++i) Sb[row * 1040 + i * 64 + lane] = (__bf16)p[j][i];
    }
    __syncthreads();

    // phase 3: value[16][64] = P @ v ; wave w does d-cols [w*16, w*16+16)
    f32x4 acc = {0.f, 0.f, 0.f, 0.f};
    const __bf16* vbase = vtb + (size_t)(bh * 64 + w * 16 + l15) * 1024 + quad * 8;
    for (int kk = 0; kk < 1024; kk += 32) {
        bf16x8 af = *(const bf16x8*)&Sb[l15 * 1040 + kk + quad * 8];
        bf16x8 bf_ = *(const bf16x8*)(vbase + kk);
        acc = __builtin_amdgcn_mfma_f32_16x16x32_bf16(af, bf_, acc, 0, 0, 0);
    }
    for (int r = 0; r < 4; ++r) {
        int mrow = quad * 4 + r;
        value_bf[(size_t)(b * 1024 + m0 + mrow) * 1024 + h * 64 + w * 16 + l15] = (__bf16)acc[r];
    }
}

// ------------------------------- out-proj GEMM: pre = x + value @ Wo^T + bo  (plain bf16)
__global__ __launch_bounds__(256) void outproj_kernel(
    const __bf16* __restrict__ vb, const __bf16* __restrict__ wob,
    const float* __restrict__ x, const float* __restrict__ bo,
    float* __restrict__ pre) {
    __shared__ __bf16 As[128 * 32];
    __shared__ __bf16 Bs[128 * 32];
    const int tid = threadIdx.x;
    const int m0 = blockIdx.y * 128;
    const int n0 = blockIdx.x * 128;
    const int lane = tid & 63, w = tid >> 6;
    const int l15 = lane & 15, quad = lane >> 4;
    const int wm = (w & 1) * 64, wn = (w >> 1) * 64;

    f32x4 acc[4][4];
    for (int i = 0; i < 4; ++i)
        for (int j = 0; j < 4; ++j)
            for (int r = 0; r < 4; ++r) acc[i][j][r] = 0.0f;

    for (int kk = 0; kk < 1024; kk += 32) {
        __syncthreads();
        for (int cc = 0; cc < 2; ++cc) {
            int c = tid + cc * 256;
            int row = c >> 2, k8 = (c & 3) * 8;
            *(bf16x8*)&As[row * 32 + k8] = *(const bf16x8*)&vb[(size_t)(m0 + row) * 1024 + kk + k8];
            *(bf16x8*)&Bs[row * 32 + k8] = *(const bf16x8*)&wob[(size_t)(n0 + row) * 1024 + kk + k8];
        }
        __syncthreads();
        bf16x8 af[4], bfr[4];
        for (int i = 0; i < 4; ++i) af[i] = *(const bf16x8*)&As[(wm + i * 16 + l15) * 32 + quad * 8];
        for (int j = 0; j < 4; ++j) bfr[j] = *(const bf16x8*)&Bs[(wn + j * 16 + l15) * 32 + quad * 8];
        for (int i = 0; i < 4; ++i)
            for (int j = 0; j < 4; ++j)
                acc[i][j] = __builtin_amdgcn_mfma_f32_16x16x32_bf16(af[i], bfr[j], acc[i][j], 0, 0, 0);
    }

    for (int i = 0; i < 4; ++i)
        for (int j = 0; j < 4; ++j)
            for (int r = 0; r < 4; ++r) {
                int m = m0 + wm + i * 16 + quad * 4 + r;
                int n = n0 + wn + j * 16 + l15;
                pre[(size_t)m * 1024 + n] = acc[i][j][r] + x[(size_t)m * 1024 + n] + bo[n];
            }
}

// ---------------------------------------------------------------- LayerNorm (in place)
__global__ __launch_bounds__(256) void ln_kernel(float* __restrict__ buf,
                                                 const float* __restrict__ gamma,
                                                 const float* __restrict__ beta) {
    const int row = blockIdx.x;
    const int tid = threadIdx.x;
    const int lane = tid & 63, w = tid >> 6;
    __shared__ float red[8];
    float* rp = buf + (size_t)row * 1024;
    float loc[4];
    float s = 0.f, s2 = 0.f;
    for (int e = 0; e < 4; ++e) {
        loc[e] = rp[tid + e * 256];
        s += loc[e];
        s2 += loc[e] * loc[e];
    }
    for (int o = 32; o > 0; o >>= 1) {
        s += __shfl_xor(s, o);
        s2 += __shfl_xor(s2, o);
    }
    if (lane == 0) { red[w * 2] = s; red[w * 2 + 1] = s2; }
    __syncthreads();
    float ts = red[0] + red[2] + red[4] + red[6];
    float ts2 = red[1] + red[3] + red[5] + red[7];
    float mu = ts * (1.0f / 1024.0f);
    float var = ts2 * (1.0f / 1024.0f) - mu * mu;
    float sc = rsqrtf(var + 1e-5f);
    for (int e = 0; e < 4; ++e) {
        int c = tid + e * 256;
        rp[c] = (loc[e] - mu) * sc * gamma[c] + beta[c];
    }
}

extern "C" void kernel_launch(void* const* d_in, const int* in_sizes, int n_in,
                              void* d_out, int out_size, void* d_ws, size_t ws_size,
                              hipStream_t stream) {
    const float* x    = (const float*)d_in[0];
    const int*   mask = (const int*)d_in[1];
    const float* Wq   = (const float*)d_in[2];
    const float* bq   = (const float*)d_in[3];
    const float* Wk   = (const float*)d_in[4];
    const float* bk   = (const float*)d_in[5];
    const float* Wv   = (const float*)d_in[6];
    const float* bv   = (const float*)d_in[7];
    const float* Wo   = (const float*)d_in[8];
    const float* bo   = (const float*)d_in[9];
    const float* gamma= (const float*)d_in[10];
    const float* beta = (const float*)d_in[11];

    char* p = (char*)d_ws;
    __bf16* xh    = (__bf16*)p; p += (size_t)4194304 * 2;   // x hi
    __bf16* xl    = (__bf16*)p; p += (size_t)4194304 * 2;   // x lo
    __bf16* wt_hi = (__bf16*)p; p += (size_t)3145728 * 2;   // Wqkv^T hi  [3072][1024]
    __bf16* wt_lo = (__bf16*)p; p += (size_t)3145728 * 2;   // Wqkv^T lo
    __bf16* wob   = (__bf16*)p; p += (size_t)1048576 * 2;   // Wo bf16 [n][k]
    __bf16* qb    = (__bf16*)p; p += (size_t)4194304 * 2;   // q [bh][l][64]
    __bf16* kb    = (__bf16*)p; p += (size_t)4194304 * 2;   // k [bh][l][64]
    __bf16* vtb   = (__bf16*)p; p += (size_t)4194304 * 2;   // v^T [bh][64][1024]
    __bf16* valb  = (__bf16*)p; p += (size_t)4194304 * 2;   // value [b*l][1024]

    float* outb  = (float*)d_out;            // [4096][1024] : pre, then LN in place
    float* atten = outb + 4194304;           // [64][1024][1024]

    split_x_kernel<<<4096, 256, 0, stream>>>(x, xh, xl);
    split_w_kernel<<<dim3(32, 2, 48), 256, 0, stream>>>(Wq, Wk, Wv, wt_hi, wt_lo);
    conv_wo_kernel<<<1024, 256, 0, stream>>>(Wo, wob);
    qkv_gemm_kernel<<<dim3(24, 32), 256, 0, stream>>>(xh, xl, wt_hi, wt_lo, bq, bk, bv, qb, kb, vtb);
    attn_kernel<<<dim3(64, 16, 4), 256, 0, stream>>>(qb, kb, vtb, mask, atten, valb);
    outproj_kernel<<<dim3(8, 32), 256, 0, stream>>>(valb, wob, x, bo, outb);
    ln_kernel<<<4096, 256, 0, stream>>>(outb, gamma, beta);
}

// Round 2
// 553.154 us; speedup vs baseline: 1.0481x; 1.0481x over previous
//
#include <hip/hip_runtime.h>
#include <hip/hip_bf16.h>

typedef __bf16 bf16x8 __attribute__((ext_vector_type(8)));
typedef __bf16 bf16x4 __attribute__((ext_vector_type(4)));
typedef float  f32x4  __attribute__((ext_vector_type(4)));

#define MIN_VALUE (-1.7014118346046923e38f)

// async global->LDS direct copy, 16 B per lane. LDS dest = wave-uniform base +
// lane*16; we pass each lane's own consistent pointer (lane0's == base).
__device__ __forceinline__ void async_load16(const __bf16* g, __bf16* l) {
    __builtin_amdgcn_global_load_lds(
        (const __attribute__((address_space(1))) uint32_t*)(uintptr_t)g,
        (__attribute__((address_space(3))) uint32_t*)(uint32_t)(uintptr_t)l,
        16, 0, 0);
}

// ---------------------------------------------------------------- x -> bf16 (hi only)
__global__ __launch_bounds__(256) void conv_x_kernel(const float* __restrict__ x,
                                                     __bf16* __restrict__ xh) {
    int i = (blockIdx.x * 256 + threadIdx.x) * 4;
    float4 v = *(const float4*)(x + i);
    float vv[4] = {v.x, v.y, v.z, v.w};
    bf16x4 h;
    for (int e = 0; e < 4; ++e) h[e] = (__bf16)vv[e];
    *(bf16x4*)(xh + i) = h;
}

// ------------------------------------------- transpose+split Wq/Wk/Wv -> [3072][1024] hi/lo
// out row n = sel*1024 + h*64 + d, col = i.  Input W[h][i][d] ([16][1024][64]).
__global__ __launch_bounds__(256) void split_w_kernel(const float* __restrict__ Wq,
                                                      const float* __restrict__ Wk,
                                                      const float* __restrict__ Wv,
                                                      __bf16* __restrict__ wh,
                                                      __bf16* __restrict__ wl) {
    __shared__ float t[32][33];
    int z = blockIdx.z;
    int sel = z >> 4, h = z & 15;
    const float* W = (sel == 0) ? Wq : (sel == 1) ? Wk : Wv;
    int i0 = blockIdx.x * 32, d0 = blockIdx.y * 32;
    int tx = threadIdx.x & 31, ty = threadIdx.x >> 5;  // 8 rows per pass
    for (int it = 0; it < 4; ++it) {
        int r = ty + it * 8;
        t[r][tx] = W[(size_t)(h * 1024 + i0 + r) * 64 + d0 + tx];
    }
    __syncthreads();
    for (int it = 0; it < 4; ++it) {
        int r = ty + it * 8;
        float v = t[tx][r];  // = W[h][i0+tx][d0+r]
        size_t o = (size_t)(sel * 1024 + h * 64 + d0 + r) * 1024 + i0 + tx;
        __bf16 hi = (__bf16)v;
        wh[o] = hi;
        wl[o] = (__bf16)(v - (float)hi);
    }
}

// ---------------------------------------------------------------- Wo -> bf16 (natural [n][k])
__global__ __launch_bounds__(256) void conv_wo_kernel(const float* __restrict__ Wo,
                                                      __bf16* __restrict__ wob) {
    int i = (blockIdx.x * 256 + threadIdx.x) * 4;
    float4 v = *(const float4*)(Wo + i);
    float vv[4] = {v.x, v.y, v.z, v.w};
    bf16x4 h;
    for (int e = 0; e < 4; ++e) h[e] = (__bf16)vv[e];
    *(bf16x4*)(wob + i) = h;
}

// ---------------------------------------------------------------- QKV GEMM (W hi/lo split)
// C[4096][3072] = xh[4096][1024] @ (Wh+Wl)^T ; W layouts [3072][1024] ([n][k]).
// Outputs: q,k as bf16 [bh][l][64]; v transposed bf16 [bh][d][1024].
__global__ __launch_bounds__(256) void qkv_gemm_kernel(
    const __bf16* __restrict__ xh,
    const __bf16* __restrict__ wh, const __bf16* __restrict__ wl,
    const float* __restrict__ bq, const float* __restrict__ bk, const float* __restrict__ bv,
    __bf16* __restrict__ qb, __bf16* __restrict__ kb, __bf16* __restrict__ vtb) {
    __shared__ __bf16 As[128 * 32];
    __shared__ __bf16 Bh[128 * 32];
    __shared__ __bf16 Bl[128 * 32];
    const int tid = threadIdx.x;
    const int m0 = blockIdx.y * 128;
    const int n0 = blockIdx.x * 128;
    const int lane = tid & 63, w = tid >> 6;
    const int l15 = lane & 15, quad = lane >> 4;
    const int wm = (w & 1) * 64, wn = (w >> 1) * 64;
    const int r4 = lane >> 2;            // 0..15 (staging row within 16)
    const int c8 = (lane & 3) * 8;       // staging col (elements)

    f32x4 acc[4][4];
    for (int i = 0; i < 4; ++i)
        for (int j = 0; j < 4; ++j)
            for (int r = 0; r < 4; ++r) acc[i][j][r] = 0.0f;

    for (int kk = 0; kk < 1024; kk += 32) {
        __syncthreads();
        // wave w stages rows [w*32, w*32+32) of each tile via global_load_lds
        for (int half = 0; half < 2; ++half) {
            int row = w * 32 + half * 16 + r4;
            int lo = w * 1024 + half * 512 + lane * 8;   // LDS element offset
            async_load16(&xh[(size_t)(m0 + row) * 1024 + kk + c8], &As[lo]);
            async_load16(&wh[(size_t)(n0 + row) * 1024 + kk + c8], &Bh[lo]);
            async_load16(&wl[(size_t)(n0 + row) * 1024 + kk + c8], &Bl[lo]);
        }
        __syncthreads();
        bf16x8 af[4], bhf[4], blf[4];
        for (int i = 0; i < 4; ++i)
            af[i] = *(const bf16x8*)&As[(wm + i * 16 + l15) * 32 + quad * 8];
        for (int j = 0; j < 4; ++j) {
            bhf[j] = *(const bf16x8*)&Bh[(wn + j * 16 + l15) * 32 + quad * 8];
            blf[j] = *(const bf16x8*)&Bl[(wn + j * 16 + l15) * 32 + quad * 8];
        }
        for (int i = 0; i < 4; ++i)
            for (int j = 0; j < 4; ++j) {
                acc[i][j] = __builtin_amdgcn_mfma_f32_16x16x32_bf16(af[i], bhf[j], acc[i][j], 0, 0, 0);
                acc[i][j] = __builtin_amdgcn_mfma_f32_16x16x32_bf16(af[i], blf[j], acc[i][j], 0, 0, 0);
            }
    }

    const int sel = n0 >> 10;
    const float* bias = (sel == 0) ? bq : (sel == 1) ? bk : bv;
    for (int i = 0; i < 4; ++i)
        for (int j = 0; j < 4; ++j)
            for (int r = 0; r < 4; ++r) {
                int m = m0 + wm + i * 16 + quad * 4 + r;
                int n = n0 + wn + j * 16 + l15;
                int nn = n & 1023;
                int h = nn >> 6, d = n & 63;
                float v = acc[i][j][r] + bias[nn];
                int bb = m >> 10, ll = m & 1023;
                if (sel == 2) {
                    vtb[(size_t)((bb * 16 + h) * 64 + d) * 1024 + ll] = (__bf16)v;
                } else {
                    __bf16* dst = (sel == 0) ? qb : kb;
                    dst[(size_t)((bb * 16 + h) * 1024 + ll) * 64 + d] = (__bf16)v;
                }
            }
}

// --------------------------------------- fused scores + mask + softmax + PV per 16-row tile
__global__ __launch_bounds__(256) void attn_kernel(
    const __bf16* __restrict__ qb, const __bf16* __restrict__ kb,
    const __bf16* __restrict__ vtb, const int* __restrict__ mask,
    float* __restrict__ atten, __bf16* __restrict__ value_bf) {
    __shared__ float S[16 * 1024];  // exactly 64 KB
    const int m0 = blockIdx.x * 16;
    const int h = blockIdx.y, b = blockIdx.z;
    const int bh = b * 16 + h;
    const int tid = threadIdx.x;
    const int lane = tid & 63, w = tid >> 6;
    const int l15 = lane & 15, quad = lane >> 4;

    // phase 1: S = (q @ k^T) * scale, masked. Physical col = col ^ (quad<<4)
    // (quad = row>>2) -> breaks the 4-way bank conflict down to free 2-way.
    const __bf16* qbase = qb + (size_t)(bh * 1024 + m0 + l15) * 64 + quad * 8;
    bf16x8 a0 = *(const bf16x8*)(qbase);
    bf16x8 a1 = *(const bf16x8*)(qbase + 32);
    const int swz1 = quad << 4;
    for (int t = 0; t < 16; ++t) {
        int n0 = w * 256 + t * 16;
        const __bf16* kbase = kb + (size_t)(bh * 1024 + n0 + l15) * 64 + quad * 8;
        bf16x8 b0 = *(const bf16x8*)(kbase);
        bf16x8 b1 = *(const bf16x8*)(kbase + 32);
        f32x4 c = {0.f, 0.f, 0.f, 0.f};
        c = __builtin_amdgcn_mfma_f32_16x16x32_bf16(a0, b0, c, 0, 0, 0);
        c = __builtin_amdgcn_mfma_f32_16x16x32_bf16(a1, b1, c, 0, 0, 0);
        int col = n0 + l15;
        bool msk = (mask[b * 1024 + col] == 0);
        for (int r = 0; r < 4; ++r) {
            float s = c[r] * 0.125f;
            if (msk) s = MIN_VALUE;
            S[(quad * 4 + r) * 1024 + (col ^ swz1)] = s;
        }
    }
    __syncthreads();

    // phase 2: softmax on rows 4w..4w+3 (values held in registers)
    float p[4][16];
    const int swz2 = w << 4;  // = (row>>2)<<4 for rows 4w..4w+3
    for (int j = 0; j < 4; ++j) {
        int row = w * 4 + j;
        float mx = -3.4e38f;
        for (int i = 0; i < 16; ++i) {
            p[j][i] = S[row * 1024 + ((i * 64 + lane) ^ swz2)];
            mx = fmaxf(mx, p[j][i]);
        }
        for (int o = 32; o > 0; o >>= 1) mx = fmaxf(mx, __shfl_xor(mx, o));
        float sum = 0.f;
        for (int i = 0; i < 16; ++i) {
            float e = __expf(p[j][i] - mx);
            p[j][i] = e;
            sum += e;
        }
        for (int o = 32; o > 0; o >>= 1) sum += __shfl_xor(sum, o);
        float inv = 1.0f / sum;
        float* out = atten + (size_t)(bh * 1024 + m0 + row) * 1024;
        for (int i = 0; i < 16; ++i) {
            p[j][i] *= inv;
            out[i * 64 + lane] = p[j][i];
        }
    }
    __syncthreads();

    // repack P to bf16 in LDS, row stride 1040 (16B aligned, low-conflict)
    __bf16* Sb = (__bf16*)S;
    for (int j = 0; j < 4; ++j) {
        int row = w * 4 + j;
        for (int i = 0; i < 16; ++i) Sb[row * 1040 + i * 64 + lane] = (__bf16)p[j][i];
    }
    __syncthreads();

    // phase 3: value[16][64] = P @ v ; wave w does d-cols [w*16, w*16+16)
    f32x4 acc = {0.f, 0.f, 0.f, 0.f};
    const __bf16* vbase = vtb + (size_t)(bh * 64 + w * 16 + l15) * 1024 + quad * 8;
    for (int kk = 0; kk < 1024; kk += 32) {
        bf16x8 af = *(const bf16x8*)&Sb[l15 * 1040 + kk + quad * 8];
        bf16x8 bf_ = *(const bf16x8*)(vbase + kk);
        acc = __builtin_amdgcn_mfma_f32_16x16x32_bf16(af, bf_, acc, 0, 0, 0);
    }
    for (int r = 0; r < 4; ++r) {
        int mrow = quad * 4 + r;
        value_bf[(size_t)(b * 1024 + m0 + mrow) * 1024 + h * 64 + w * 16 + l15] = (__bf16)acc[r];
    }
}

// ------------------------------- out-proj GEMM: pre = x + value @ Wo^T + bo  (plain bf16)
__global__ __launch_bounds__(256) void outproj_kernel(
    const __bf16* __restrict__ vb, const __bf16* __restrict__ wob,
    const float* __restrict__ x, const float* __restrict__ bo,
    float* __restrict__ pre) {
    __shared__ __bf16 As[128 * 32];
    __shared__ __bf16 Bs[128 * 32];
    const int tid = threadIdx.x;
    const int m0 = blockIdx.y * 128;
    const int n0 = blockIdx.x * 128;
    const int lane = tid & 63, w = tid >> 6;
    const int l15 = lane & 15, quad = lane >> 4;
    const int wm = (w & 1) * 64, wn = (w >> 1) * 64;
    const int r4 = lane >> 2;
    const int c8 = (lane & 3) * 8;

    f32x4 acc[4][4];
    for (int i = 0; i < 4; ++i)
        for (int j = 0; j < 4; ++j)
            for (int r = 0; r < 4; ++r) acc[i][j][r] = 0.0f;

    for (int kk = 0; kk < 1024; kk += 32) {
        __syncthreads();
        for (int half = 0; half < 2; ++half) {
            int row = w * 32 + half * 16 + r4;
            int lo = w * 1024 + half * 512 + lane * 8;
            async_load16(&vb[(size_t)(m0 + row) * 1024 + kk + c8], &As[lo]);
            async_load16(&wob[(size_t)(n0 + row) * 1024 + kk + c8], &Bs[lo]);
        }
        __syncthreads();
        bf16x8 af[4], bfr[4];
        for (int i = 0; i < 4; ++i) af[i] = *(const bf16x8*)&As[(wm + i * 16 + l15) * 32 + quad * 8];
        for (int j = 0; j < 4; ++j) bfr[j] = *(const bf16x8*)&Bs[(wn + j * 16 + l15) * 32 + quad * 8];
        for (int i = 0; i < 4; ++i)
            for (int j = 0; j < 4; ++j)
                acc[i][j] = __builtin_amdgcn_mfma_f32_16x16x32_bf16(af[i], bfr[j], acc[i][j], 0, 0, 0);
    }

    for (int i = 0; i < 4; ++i)
        for (int j = 0; j < 4; ++j)
            for (int r = 0; r < 4; ++r) {
                int m = m0 + wm + i * 16 + quad * 4 + r;
                int n = n0 + wn + j * 16 + l15;
                pre[(size_t)m * 1024 + n] = acc[i][j][r] + x[(size_t)m * 1024 + n] + bo[n];
            }
}

// ---------------------------------------------------------------- LayerNorm (in place)
__global__ __launch_bounds__(256) void ln_kernel(float* __restrict__ buf,
                                                 const float* __restrict__ gamma,
                                                 const float* __restrict__ beta) {
    const int row = blockIdx.x;
    const int tid = threadIdx.x;
    const int lane = tid & 63, w = tid >> 6;
    __shared__ float red[8];
    float* rp = buf + (size_t)row * 1024;
    float loc[4];
    float s = 0.f, s2 = 0.f;
    for (int e = 0; e < 4; ++e) {
        loc[e] = rp[tid + e * 256];
        s += loc[e];
        s2 += loc[e] * loc[e];
    }
    for (int o = 32; o > 0; o >>= 1) {
        s += __shfl_xor(s, o);
        s2 += __shfl_xor(s2, o);
    }
    if (lane == 0) { red[w * 2] = s; red[w * 2 + 1] = s2; }
    __syncthreads();
    float ts = red[0] + red[2] + red[4] + red[6];
    float ts2 = red[1] + red[3] + red[5] + red[7];
    float mu = ts * (1.0f / 1024.0f);
    float var = ts2 * (1.0f / 1024.0f) - mu * mu;
    float sc = rsqrtf(var + 1e-5f);
    for (int e = 0; e < 4; ++e) {
        int c = tid + e * 256;
        rp[c] = (loc[e] - mu) * sc * gamma[c] + beta[c];
    }
}

extern "C" void kernel_launch(void* const* d_in, const int* in_sizes, int n_in,
                              void* d_out, int out_size, void* d_ws, size_t ws_size,
                              hipStream_t stream) {
    const float* x    = (const float*)d_in[0];
    const int*   mask = (const int*)d_in[1];
    const float* Wq   = (const float*)d_in[2];
    const float* bq   = (const float*)d_in[3];
    const float* Wk   = (const float*)d_in[4];
    const float* bk   = (const float*)d_in[5];
    const float* Wv   = (const float*)d_in[6];
    const float* bv   = (const float*)d_in[7];
    const float* Wo   = (const float*)d_in[8];
    const float* bo   = (const float*)d_in[9];
    const float* gamma= (const float*)d_in[10];
    const float* beta = (const float*)d_in[11];

    char* p = (char*)d_ws;
    __bf16* xh    = (__bf16*)p; p += (size_t)4194304 * 2;   // x bf16
    __bf16* wt_hi = (__bf16*)p; p += (size_t)3145728 * 2;   // Wqkv^T hi  [3072][1024]
    __bf16* wt_lo = (__bf16*)p; p += (size_t)3145728 * 2;   // Wqkv^T lo
    __bf16* wob   = (__bf16*)p; p += (size_t)1048576 * 2;   // Wo bf16 [n][k]
    __bf16* qb    = (__bf16*)p; p += (size_t)4194304 * 2;   // q [bh][l][64]
    __bf16* kb    = (__bf16*)p; p += (size_t)4194304 * 2;   // k [bh][l][64]
    __bf16* vtb   = (__bf16*)p; p += (size_t)4194304 * 2;   // v^T [bh][64][1024]
    __bf16* valb  = (__bf16*)p; p += (size_t)4194304 * 2;   // value [b*l][1024]

    float* outb  = (float*)d_out;            // [4096][1024] : pre, then LN in place
    float* atten = outb + 4194304;           // [64][1024][1024]

    conv_x_kernel<<<4096, 256, 0, stream>>>(x, xh);
    split_w_kernel<<<dim3(32, 2, 48), 256, 0, stream>>>(Wq, Wk, Wv, wt_hi, wt_lo);
    conv_wo_kernel<<<1024, 256, 0, stream>>>(Wo, wob);
    qkv_gemm_kernel<<<dim3(24, 32), 256, 0, stream>>>(xh, wt_hi, wt_lo, bq, bk, bv, qb, kb, vtb);
    attn_kernel<<<dim3(64, 16, 4), 256, 0, stream>>>(qb, kb, vtb, mask, atten, valb);
    outproj_kernel<<<dim3(8, 32), 256, 0, stream>>>(valb, wob, x, bo, outb);
    ln_kernel<<<4096, 256, 0, stream>>>(outb, gamma, beta);
}

// Round 3
// 522.185 us; speedup vs baseline: 1.1103x; 1.0593x over previous
//
#include <hip/hip_runtime.h>
#include <hip/hip_bf16.h>

typedef __bf16 bf16x8 __attribute__((ext_vector_type(8)));
typedef __bf16 bf16x4 __attribute__((ext_vector_type(4)));
typedef float  f32x4  __attribute__((ext_vector_type(4)));

#define MIN_VALUE (-1.7014118346046923e38f)

// async global->LDS direct copy, 16 B per lane. LDS dest = wave-uniform base +
// lane*16; we pass each lane's own consistent pointer (lane0's == base).
__device__ __forceinline__ void async_load16(const __bf16* g, __bf16* l) {
    __builtin_amdgcn_global_load_lds(
        (const __attribute__((address_space(1))) uint32_t*)(uintptr_t)g,
        (__attribute__((address_space(3))) uint32_t*)(uint32_t)(uintptr_t)l,
        16, 0, 0);
}

// ---------------------------------------------------------------- x -> bf16 (hi only)
__global__ __launch_bounds__(256) void conv_x_kernel(const float* __restrict__ x,
                                                     __bf16* __restrict__ xh) {
    int i = (blockIdx.x * 256 + threadIdx.x) * 4;
    float4 v = *(const float4*)(x + i);
    float vv[4] = {v.x, v.y, v.z, v.w};
    bf16x4 h;
    for (int e = 0; e < 4; ++e) h[e] = (__bf16)vv[e];
    *(bf16x4*)(xh + i) = h;
}

// ------------------------------------------- transpose+split Wq/Wk/Wv -> [3072][1024] hi/lo
__global__ __launch_bounds__(256) void split_w_kernel(const float* __restrict__ Wq,
                                                      const float* __restrict__ Wk,
                                                      const float* __restrict__ Wv,
                                                      __bf16* __restrict__ wh,
                                                      __bf16* __restrict__ wl) {
    __shared__ float t[32][33];
    int z = blockIdx.z;
    int sel = z >> 4, h = z & 15;
    const float* W = (sel == 0) ? Wq : (sel == 1) ? Wk : Wv;
    int i0 = blockIdx.x * 32, d0 = blockIdx.y * 32;
    int tx = threadIdx.x & 31, ty = threadIdx.x >> 5;
    for (int it = 0; it < 4; ++it) {
        int r = ty + it * 8;
        t[r][tx] = W[(size_t)(h * 1024 + i0 + r) * 64 + d0 + tx];
    }
    __syncthreads();
    for (int it = 0; it < 4; ++it) {
        int r = ty + it * 8;
        float v = t[tx][r];
        size_t o = (size_t)(sel * 1024 + h * 64 + d0 + r) * 1024 + i0 + tx;
        __bf16 hi = (__bf16)v;
        wh[o] = hi;
        wl[o] = (__bf16)(v - (float)hi);
    }
}

// ---------------------------------------------------------------- Wo -> bf16 (natural [n][k])
__global__ __launch_bounds__(256) void conv_wo_kernel(const float* __restrict__ Wo,
                                                      __bf16* __restrict__ wob) {
    int i = (blockIdx.x * 256 + threadIdx.x) * 4;
    float4 v = *(const float4*)(Wo + i);
    float vv[4] = {v.x, v.y, v.z, v.w};
    bf16x4 h;
    for (int e = 0; e < 4; ++e) h[e] = (__bf16)vv[e];
    *(bf16x4*)(wob + i) = h;
}

// ---------------------------------------------------------------- QKV GEMM (W hi/lo split)
// C[4096][3072] = xh[4096][1024] @ (Wh+Wl)^T ; lo-pass skipped for the v third
// (v precision governed by the loose out threshold).
__global__ __launch_bounds__(256) void qkv_gemm_kernel(
    const __bf16* __restrict__ xh,
    const __bf16* __restrict__ wh, const __bf16* __restrict__ wl,
    const float* __restrict__ bq, const float* __restrict__ bk, const float* __restrict__ bv,
    __bf16* __restrict__ qb, __bf16* __restrict__ kb, __bf16* __restrict__ vtb) {
    __shared__ __bf16 As[128 * 32];
    __shared__ __bf16 Bh[128 * 32];
    __shared__ __bf16 Bl[128 * 32];
    const int tid = threadIdx.x;
    const int m0 = blockIdx.y * 128;
    const int n0 = blockIdx.x * 128;
    const int lane = tid & 63, w = tid >> 6;
    const int l15 = lane & 15, quad = lane >> 4;
    const int wm = (w & 1) * 64, wn = (w >> 1) * 64;
    const int r4 = lane >> 2;
    const int c8 = (lane & 3) * 8;
    const bool need_lo = (n0 < 2048);   // q,k blocks only

    f32x4 acc[4][4];
    for (int i = 0; i < 4; ++i)
        for (int j = 0; j < 4; ++j)
            for (int r = 0; r < 4; ++r) acc[i][j][r] = 0.0f;

    for (int kk = 0; kk < 1024; kk += 32) {
        __syncthreads();
        for (int half = 0; half < 2; ++half) {
            int row = w * 32 + half * 16 + r4;
            int lo = w * 1024 + half * 512 + lane * 8;
            async_load16(&xh[(size_t)(m0 + row) * 1024 + kk + c8], &As[lo]);
            async_load16(&wh[(size_t)(n0 + row) * 1024 + kk + c8], &Bh[lo]);
            if (need_lo)
                async_load16(&wl[(size_t)(n0 + row) * 1024 + kk + c8], &Bl[lo]);
        }
        __syncthreads();
        bf16x8 af[4], bhf[4], blf[4];
        for (int i = 0; i < 4; ++i)
            af[i] = *(const bf16x8*)&As[(wm + i * 16 + l15) * 32 + quad * 8];
        for (int j = 0; j < 4; ++j)
            bhf[j] = *(const bf16x8*)&Bh[(wn + j * 16 + l15) * 32 + quad * 8];
        if (need_lo)
            for (int j = 0; j < 4; ++j)
                blf[j] = *(const bf16x8*)&Bl[(wn + j * 16 + l15) * 32 + quad * 8];
        for (int i = 0; i < 4; ++i)
            for (int j = 0; j < 4; ++j)
                acc[i][j] = __builtin_amdgcn_mfma_f32_16x16x32_bf16(af[i], bhf[j], acc[i][j], 0, 0, 0);
        if (need_lo)
            for (int i = 0; i < 4; ++i)
                for (int j = 0; j < 4; ++j)
                    acc[i][j] = __builtin_amdgcn_mfma_f32_16x16x32_bf16(af[i], blf[j], acc[i][j], 0, 0, 0);
    }

    const int sel = n0 >> 10;
    const float* bias = (sel == 0) ? bq : (sel == 1) ? bk : bv;
    for (int i = 0; i < 4; ++i)
        for (int j = 0; j < 4; ++j)
            for (int r = 0; r < 4; ++r) {
                int m = m0 + wm + i * 16 + quad * 4 + r;
                int n = n0 + wn + j * 16 + l15;
                int nn = n & 1023;
                int h = nn >> 6, d = n & 63;
                float v = acc[i][j][r] + bias[nn];
                int bb = m >> 10, ll = m & 1023;
                if (sel == 2) {
                    vtb[(size_t)((bb * 16 + h) * 64 + d) * 1024 + ll] = (__bf16)v;
                } else {
                    __bf16* dst = (sel == 0) ? qb : kb;
                    dst[(size_t)((bb * 16 + h) * 1024 + ll) * 64 + d] = (__bf16)v;
                }
            }
}

// --------------------------------------- fused scores + mask + softmax + PV per 16-row tile
// S kept in registers (wave w owns cols [w*256, w*256+256)); cross-wave max/sum
// via tiny LDS buffers; only bf16 P goes through LDS (PV operand transpose).
// PV runs on UNnormalized P; 1/sum folded into the PV epilogue.
__global__ __launch_bounds__(256, 4) void attn_kernel(
    const __bf16* __restrict__ qb, const __bf16* __restrict__ kb,
    const __bf16* __restrict__ vtb, const int* __restrict__ mask,
    float* __restrict__ atten, __bf16* __restrict__ value_bf) {
    __shared__ __bf16 P[16 * 1048];     // 32.75 KB, stride 1048 -> 2-way banks (free)
    __shared__ float red[2][4][16];     // [max/sum][wave][row]
    const int m0 = blockIdx.x * 16;
    const int h = blockIdx.y, b = blockIdx.z;
    const int bh = b * 16 + h;
    const int tid = threadIdx.x;
    const int lane = tid & 63, w = tid >> 6;
    const int l15 = lane & 15, quad = lane >> 4;

    // phase 1: scores in registers. C layout: row=quad*4+r, col=n0+l15.
    const __bf16* qbase = qb + (size_t)(bh * 1024 + m0 + l15) * 64 + quad * 8;
    bf16x8 a0 = *(const bf16x8*)(qbase);
    bf16x8 a1 = *(const bf16x8*)(qbase + 32);
    f32x4 s[16];
    for (int t = 0; t < 16; ++t) {
        int n0 = w * 256 + t * 16;
        const __bf16* kbase = kb + (size_t)(bh * 1024 + n0 + l15) * 64 + quad * 8;
        bf16x8 b0 = *(const bf16x8*)(kbase);
        bf16x8 b1 = *(const bf16x8*)(kbase + 32);
        f32x4 c = {0.f, 0.f, 0.f, 0.f};
        c = __builtin_amdgcn_mfma_f32_16x16x32_bf16(a0, b0, c, 0, 0, 0);
        c = __builtin_amdgcn_mfma_f32_16x16x32_bf16(a1, b1, c, 0, 0, 0);
        bool msk = (mask[b * 1024 + n0 + l15] == 0);
        for (int r = 0; r < 4; ++r) s[t][r] = msk ? MIN_VALUE : c[r] * 0.125f;
    }

    // phase 2a: row maxes (lane-local over t, shuffle over l15, LDS over waves)
    float mx[4];
    for (int r = 0; r < 4; ++r) {
        float m = s[0][r];
        for (int t = 1; t < 16; ++t) m = fmaxf(m, s[t][r]);
        for (int o = 1; o < 16; o <<= 1) m = fmaxf(m, __shfl_xor(m, o));
        mx[r] = m;
    }
    if (l15 == 0)
        for (int r = 0; r < 4; ++r) red[0][w][quad * 4 + r] = mx[r];
    __syncthreads();
    for (int r = 0; r < 4; ++r) {
        int row = quad * 4 + r;
        mx[r] = fmaxf(fmaxf(red[0][0][row], red[0][1][row]),
                      fmaxf(red[0][2][row], red[0][3][row]));
    }

    // phase 2b: exp (unnormalized), bf16 P to LDS, row sums
    float sum[4] = {0.f, 0.f, 0.f, 0.f};
    for (int t = 0; t < 16; ++t)
        for (int r = 0; r < 4; ++r) {
            float e = __expf(s[t][r] - mx[r]);
            s[t][r] = e;
            sum[r] += e;
            P[(quad * 4 + r) * 1048 + w * 256 + t * 16 + l15] = (__bf16)e;
        }
    for (int r = 0; r < 4; ++r) {
        float sm = sum[r];
        for (int o = 1; o < 16; o <<= 1) sm += __shfl_xor(sm, o);
        sum[r] = sm;
    }
    if (l15 == 0)
        for (int r = 0; r < 4; ++r) red[1][w][quad * 4 + r] = sum[r];
    __syncthreads();   // covers P writes AND sum reduction
    float inv[4];
    for (int r = 0; r < 4; ++r) {
        int row = quad * 4 + r;
        inv[r] = 1.0f / (red[1][0][row] + red[1][1][row] +
                         red[1][2][row] + red[1][3][row]);
    }

    // phase 2c: store normalized atten straight from registers
    for (int r = 0; r < 4; ++r) {
        float* out = atten + (size_t)(bh * 1024 + m0 + quad * 4 + r) * 1024 + w * 256 + l15;
        for (int t = 0; t < 16; ++t) out[t * 16] = s[t][r] * inv[r];
    }

    // phase 3: value = (P @ v) * inv ; wave w does d-cols [w*16, w*16+16)
    f32x4 acc = {0.f, 0.f, 0.f, 0.f};
    const __bf16* vbase = vtb + (size_t)(bh * 64 + w * 16 + l15) * 1024 + quad * 8;
    for (int kk = 0; kk < 1024; kk += 32) {
        bf16x8 af = *(const bf16x8*)&P[l15 * 1048 + kk + quad * 8];
        bf16x8 bf_ = *(const bf16x8*)(vbase + kk);
        acc = __builtin_amdgcn_mfma_f32_16x16x32_bf16(af, bf_, acc, 0, 0, 0);
    }
    for (int r = 0; r < 4; ++r) {
        int mrow = quad * 4 + r;
        value_bf[(size_t)(b * 1024 + m0 + mrow) * 1024 + h * 64 + w * 16 + l15] =
            (__bf16)(acc[r] * inv[r]);
    }
}

// ------------------------------- out-proj GEMM: pre = x + value @ Wo^T + bo  (plain bf16)
__global__ __launch_bounds__(256) void outproj_kernel(
    const __bf16* __restrict__ vb, const __bf16* __restrict__ wob,
    const float* __restrict__ x, const float* __restrict__ bo,
    float* __restrict__ pre) {
    __shared__ __bf16 As[128 * 32];
    __shared__ __bf16 Bs[128 * 32];
    const int tid = threadIdx.x;
    const int m0 = blockIdx.y * 128;
    const int n0 = blockIdx.x * 128;
    const int lane = tid & 63, w = tid >> 6;
    const int l15 = lane & 15, quad = lane >> 4;
    const int wm = (w & 1) * 64, wn = (w >> 1) * 64;
    const int r4 = lane >> 2;
    const int c8 = (lane & 3) * 8;

    f32x4 acc[4][4];
    for (int i = 0; i < 4; ++i)
        for (int j = 0; j < 4; ++j)
            for (int r = 0; r < 4; ++r) acc[i][j][r] = 0.0f;

    for (int kk = 0; kk < 1024; kk += 32) {
        __syncthreads();
        for (int half = 0; half < 2; ++half) {
            int row = w * 32 + half * 16 + r4;
            int lo = w * 1024 + half * 512 + lane * 8;
            async_load16(&vb[(size_t)(m0 + row) * 1024 + kk + c8], &As[lo]);
            async_load16(&wob[(size_t)(n0 + row) * 1024 + kk + c8], &Bs[lo]);
        }
        __syncthreads();
        bf16x8 af[4], bfr[4];
        for (int i = 0; i < 4; ++i) af[i] = *(const bf16x8*)&As[(wm + i * 16 + l15) * 32 + quad * 8];
        for (int j = 0; j < 4; ++j) bfr[j] = *(const bf16x8*)&Bs[(wn + j * 16 + l15) * 32 + quad * 8];
        for (int i = 0; i < 4; ++i)
            for (int j = 0; j < 4; ++j)
                acc[i][j] = __builtin_amdgcn_mfma_f32_16x16x32_bf16(af[i], bfr[j], acc[i][j], 0, 0, 0);
    }

    for (int i = 0; i < 4; ++i)
        for (int j = 0; j < 4; ++j)
            for (int r = 0; r < 4; ++r) {
                int m = m0 + wm + i * 16 + quad * 4 + r;
                int n = n0 + wn + j * 16 + l15;
                pre[(size_t)m * 1024 + n] = acc[i][j][r] + x[(size_t)m * 1024 + n] + bo[n];
            }
}

// ---------------------------------------------------------------- LayerNorm (in place)
__global__ __launch_bounds__(256) void ln_kernel(float* __restrict__ buf,
                                                 const float* __restrict__ gamma,
                                                 const float* __restrict__ beta) {
    const int row = blockIdx.x;
    const int tid = threadIdx.x;
    const int lane = tid & 63, w = tid >> 6;
    __shared__ float red[8];
    float* rp = buf + (size_t)row * 1024;
    float loc[4];
    float s = 0.f, s2 = 0.f;
    for (int e = 0; e < 4; ++e) {
        loc[e] = rp[tid + e * 256];
        s += loc[e];
        s2 += loc[e] * loc[e];
    }
    for (int o = 32; o > 0; o >>= 1) {
        s += __shfl_xor(s, o);
        s2 += __shfl_xor(s2, o);
    }
    if (lane == 0) { red[w * 2] = s; red[w * 2 + 1] = s2; }
    __syncthreads();
    float ts = red[0] + red[2] + red[4] + red[6];
    float ts2 = red[1] + red[3] + red[5] + red[7];
    float mu = ts * (1.0f / 1024.0f);
    float var = ts2 * (1.0f / 1024.0f) - mu * mu;
    float sc = rsqrtf(var + 1e-5f);
    for (int e = 0; e < 4; ++e) {
        int c = tid + e * 256;
        rp[c] = (loc[e] - mu) * sc * gamma[c] + beta[c];
    }
}

extern "C" void kernel_launch(void* const* d_in, const int* in_sizes, int n_in,
                              void* d_out, int out_size, void* d_ws, size_t ws_size,
                              hipStream_t stream) {
    const float* x    = (const float*)d_in[0];
    const int*   mask = (const int*)d_in[1];
    const float* Wq   = (const float*)d_in[2];
    const float* bq   = (const float*)d_in[3];
    const float* Wk   = (const float*)d_in[4];
    const float* bk   = (const float*)d_in[5];
    const float* Wv   = (const float*)d_in[6];
    const float* bv   = (const float*)d_in[7];
    const float* Wo   = (const float*)d_in[8];
    const float* bo   = (const float*)d_in[9];
    const float* gamma= (const float*)d_in[10];
    const float* beta = (const float*)d_in[11];

    char* p = (char*)d_ws;
    __bf16* xh    = (__bf16*)p; p += (size_t)4194304 * 2;   // x bf16
    __bf16* wt_hi = (__bf16*)p; p += (size_t)3145728 * 2;   // Wqkv^T hi  [3072][1024]
    __bf16* wt_lo = (__bf16*)p; p += (size_t)3145728 * 2;   // Wqkv^T lo
    __bf16* wob   = (__bf16*)p; p += (size_t)1048576 * 2;   // Wo bf16 [n][k]
    __bf16* qb    = (__bf16*)p; p += (size_t)4194304 * 2;   // q [bh][l][64]
    __bf16* kb    = (__bf16*)p; p += (size_t)4194304 * 2;   // k [bh][l][64]
    __bf16* vtb   = (__bf16*)p; p += (size_t)4194304 * 2;   // v^T [bh][64][1024]
    __bf16* valb  = (__bf16*)p; p += (size_t)4194304 * 2;   // value [b*l][1024]

    float* outb  = (float*)d_out;            // [4096][1024] : pre, then LN in place
    float* atten = outb + 4194304;           // [64][1024][1024]

    conv_x_kernel<<<4096, 256, 0, stream>>>(x, xh);
    split_w_kernel<<<dim3(32, 2, 48), 256, 0, stream>>>(Wq, Wk, Wv, wt_hi, wt_lo);
    conv_wo_kernel<<<1024, 256, 0, stream>>>(Wo, wob);
    qkv_gemm_kernel<<<dim3(24, 32), 256, 0, stream>>>(xh, wt_hi, wt_lo, bq, bk, bv, qb, kb, vtb);
    attn_kernel<<<dim3(64, 16, 4), 256, 0, stream>>>(qb, kb, vtb, mask, atten, valb);
    outproj_kernel<<<dim3(8, 32), 256, 0, stream>>>(valb, wob, x, bo, outb);
    ln_kernel<<<4096, 256, 0, stream>>>(outb, gamma, beta);
}